// Round 16
// baseline (271.245 us; speedup 1.0000x reference)
//
#include <hip/hip_runtime.h>
#include <hip/hip_bf16.h>
#include <stdint.h>

#define B_   8
#define NS_  8192
#define E_   32
#define NT_  8192
#define NH_  10
#define NSC_ 256   // NS_/32 sub-chunks (32 s each)
#define SCAP 128   // per-segment candidate cap

typedef __bf16 bf16x8 __attribute__((ext_vector_type(8)));
typedef float  f32x4  __attribute__((ext_vector_type(4)));
typedef unsigned short ushort8_t __attribute__((ext_vector_type(8)));
typedef unsigned short ushort2_t __attribute__((ext_vector_type(2)));

static __device__ inline unsigned short f2bf(float f) {
  __hip_bfloat16 h = __float2bfloat16(f);
  return *reinterpret_cast<unsigned short*>(&h);
}
static __device__ inline float bf2f(unsigned short u) {
  __hip_bfloat16 h;
  *reinterpret_cast<unsigned short*>(&h) = u;
  return __bfloat162float(h);
}

// 10th-smallest of the 64 per-lane values (lane-tagged u64 keys; exact).
static __device__ inline float tenth_smallest(float v, int lane) {
  unsigned long long kv =
      ((unsigned long long)__float_as_uint(v) << 32) | (unsigned)lane;
  float out = 0.f;
#pragma unroll
  for (int k = 0; k < NH_; ++k) {
    unsigned long long m = kv;
#pragma unroll
    for (int off = 32; off > 0; off >>= 1) {
      const unsigned long long o = __shfl_xor(m, off, 64);
      m = o < m ? o : m;
    }
    if (kv == m) kv = ~0ull;  // self-remove (unique by lane tag)
    if (k == NH_ - 1) out = __uint_as_float((unsigned)(m >> 32));
  }
  return out;
}

// ---------------------------------------------------------------------------
// MEGA kernel: grid-fused xinter (blocks 0..255) + topk (blocks 256..8447).
// v16: xinter path gets its double-buffer back (32-s sub-chunks, 2x16KB) +
// counted vmcnt(2) waits (r8-verified pipeline) + setprio(1) so the
// critical-path xinter waves win issue arbitration over memory-stalled
// topk waves (T5 positive regime: independent mixed waves on one CU).
// LDS: union(xi 37KB, tk 4.2KB) => 4 blocks/CU, 32 waves.
// ---------------------------------------------------------------------------
union __align__(16) SharedU {
  struct {
    unsigned short Xl[2][4][256][8];   // 32 KB double-buffered A-tiles
    unsigned short Rl[2][4][16][8];    // 2 KB  B-fragments [gng][gk][t][slot]
    float RsumP[16][32];               // 2 KB
    float RsumInv[32];                 // 128 B
  } xi;
  struct {
    int cnt[8];
    unsigned int cand[8][SCAP];        // 4 KB
  } tk;
};

__global__ __launch_bounds__(512) void mega_kernel(
    const float* __restrict__ rel_lon, const float* __restrict__ rel_lat,
    float* __restrict__ out_d, float* __restrict__ out_lon,
    float* __restrict__ out_lat, int* __restrict__ idx_out,
    const unsigned short* __restrict__ XT2, const float* __restrict__ cs,
    const float* __restrict__ ct, float* __restrict__ out_xi)
{
#pragma clang fp contract(off)
  __shared__ SharedU sh;
  const int tid = threadIdx.x;

  if (blockIdx.x < 256) {
    // =====================================================================
    // xinter path: out[be][t] = (sum_s XT[be][s]*r(t,s)) / rsum[t]
    // 8 waves = 4 mg x 2 ng. Per 32-s sub-chunk: stage NEXT sub-chunk
    // (async, 2x1KB/wave), gen 32t x 32s r-tile once (strict bit-exact
    // d2, r=rsq), vmcnt(2)-counted wait, MFMA (K=32, 4 per wave).
    // =====================================================================
    __builtin_amdgcn_s_setprio(1);   // critical path: win issue arbitration

    const int w = tid >> 6, l = tid & 63;
    const int mg = w >> 1, ng = w & 1;
    const int lcol = l & 15, lkg = l >> 4;
    const int t0 = blockIdx.x * 32;

    // gen role: thread covers t = t0+gt, s-pair gq*2 within each sub-chunk
    const int gt = tid & 31;
    const int gq = tid >> 5;             // 0..15
    const int gng = gt >> 4, glc = gt & 15;
    const int gk = gq >> 2;              // kidx 0..3 within sub-chunk
    const int gsl = (gq & 3) * 2;        // slot base 0/2/4/6
    const float2 ctg = ((const float2*)ct)[t0 + gt];
    const float t2g = ctg.x * ctg.x + ctg.y * ctg.y;   // strict rn
    float rpart = 0.f;

    const int t = t0 + ng * 16 + lcol;

    f32x4 acc[4];
#pragma unroll
    for (int m = 0; m < 4; ++m)
#pragma unroll
      for (int j = 0; j < 4; ++j) acc[m][j] = 0.f;

    // stage sub-chunk sc into buffer buf: wave w covers kid=w>>1,
    // be-half=w&1 (2 x 1KB loads, lane-consecutive 16B).
#define STAGE_SC(buf, sc)                                                    \
    {                                                                        \
      const unsigned short* gbase =                                          \
          XT2 + ((size_t)(((sc) >> 1) * 8 + ((sc)&1) * 4 + (w >> 1))) * 2048 \
              + (w & 1) * 1024 + (size_t)l * 8;                              \
      __builtin_amdgcn_global_load_lds(                                      \
          (const __attribute__((address_space(1))) void*)gbase,              \
          (__attribute__((address_space(3))) void*)                          \
              &sh.xi.Xl[buf][w >> 1][(w & 1) * 128][0], 16, 0, 0);           \
      __builtin_amdgcn_global_load_lds(                                      \
          (const __attribute__((address_space(1))) void*)(gbase + 512),      \
          (__attribute__((address_space(3))) void*)                          \
              &sh.xi.Xl[buf][w >> 1][(w & 1) * 128 + 64][0], 16, 0, 0);      \
    }

    STAGE_SC(0, 0)   // prologue
    int cur = 0;
    for (int sc = 0; sc < NSC_; ++sc) {
      const bool more = (sc + 1 < NSC_);
      if (more) STAGE_SC(cur ^ 1, sc + 1)

      // ---- gen 2 r-values (strict bit-exact d2) into Rl ----
      {
        const int sb = sc * 32 + gq * 2;
        const float4 cA = *(const float4*)&cs[2 * sb];  // (sx0,sy0,sx1,sy1)
        ushort2_t ro;
#pragma unroll
        for (int j = 0; j < 2; ++j) {
          const float sx = (j == 0) ? cA.x : cA.z;
          const float sy = (j == 0) ? cA.y : cA.w;
          const float s2 = sx * sx + sy * sy;        // strict rn
          const float p0 = ctg.x * sx;               // strict rn, k=0
          const float dot = fmaf(ctg.y, sy, p0);     // explicit fma, k=1
          const float ts = t2g + s2;                 // strict rn
          float d2 = ts - 2.0f * dot;                // 2*dot exact
          d2 = fmaxf(d2, 1e-12f);
          const float r = __builtin_amdgcn_rsqf(d2);
          const unsigned short ub = f2bf(r);
          ro[j] = ub;
          rpart += bf2f(ub);
        }
        *(ushort2_t*)&sh.xi.Rl[gng][gk][glc][gsl] = ro;
      }
      // current sub-chunk's 2 loads landed (next's 2 stay in flight)
      if (more)
        asm volatile("s_waitcnt vmcnt(2) lgkmcnt(0)" ::: "memory");
      else
        asm volatile("s_waitcnt vmcnt(0) lgkmcnt(0)" ::: "memory");
      __builtin_amdgcn_s_barrier();   // Xl[cur] + Rl ready

#pragma unroll
      for (int m = 0; m < 4; ++m) {
        const bf16x8 a =
            *(const bf16x8*)&sh.xi.Xl[cur][lkg][(mg * 4 + m) * 16 + lcol][0];
        const bf16x8 Bf = *(const bf16x8*)&sh.xi.Rl[ng][lkg][lcol][0];
        acc[m] = __builtin_amdgcn_mfma_f32_16x16x32_bf16(a, Bf, acc[m], 0, 0, 0);
      }
      __builtin_amdgcn_s_barrier();   // reads done before overwrite
      cur ^= 1;
    }
#undef STAGE_SC

    // ---- rsum reduction: 16 partials per t ----
    sh.xi.RsumP[gq][gt] = rpart;
    asm volatile("s_waitcnt lgkmcnt(0)" ::: "memory");
    __builtin_amdgcn_s_barrier();
    if (tid < 32) {
      float ssum = 0.f;
#pragma unroll
      for (int qq = 0; qq < 16; ++qq) ssum += sh.xi.RsumP[qq][tid];
      sh.xi.RsumInv[tid] = 1.0f / ssum;
    }
    asm volatile("s_waitcnt lgkmcnt(0)" ::: "memory");
    __builtin_amdgcn_s_barrier();
    const float ri = sh.xi.RsumInv[ng * 16 + lcol];

    // C/D layout: lane l reg j -> row(be) = lkg*4 + j, col(t) = lcol.
#pragma unroll
    for (int m = 0; m < 4; ++m) {
      const int be0 = (mg * 4 + m) * 16 + lkg * 4;
      const int b = be0 >> 5, e = be0 & 31;
      float4 o;
      o.x = acc[m][0] * ri;
      o.y = acc[m][1] * ri;
      o.z = acc[m][2] * ri;
      o.w = acc[m][3] * ri;
      *(float4*)&out_xi[((size_t)b * NT_ + t) * E_ + e] = o;
    }
  } else {
    // =====================================================================
    // topk path (r13/r15 VERIFIED structure, 8 segments of 1024 elems).
    // =====================================================================
    const int q = tid >> 6;       // segment index (0..7)
    const int lane = tid & 63;
    const int t = blockIdx.x - 256;
    const float* lon_row = rel_lon + (size_t)t * NS_;
    const float* lat_row = rel_lat + (size_t)t * NS_;
    const int base = q * 1024;
    const float4* lon4 = (const float4*)(lon_row + base);
    const float4* lat4 = (const float4*)(lat_row + base);

    if (lane == 0) sh.tk.cnt[q] = 0;

    float d2v[4][4];
    float lmin = __uint_as_float(0x7f800000u);  // +inf
#pragma unroll
    for (int p = 0; p < 4; ++p) {
      const float4 lo = lon4[p * 64 + lane];
      const float4 la = lat4[p * 64 + lane];
      d2v[p][0] = __fmaf_rn(lo.x, lo.x, __fmul_rn(la.x, la.x));
      d2v[p][1] = __fmaf_rn(lo.y, lo.y, __fmul_rn(la.y, la.y));
      d2v[p][2] = __fmaf_rn(lo.z, lo.z, __fmul_rn(la.z, la.z));
      d2v[p][3] = __fmaf_rn(lo.w, lo.w, __fmul_rn(la.w, la.w));
      lmin = fminf(lmin, fminf(fminf(d2v[p][0], d2v[p][1]),
                               fminf(d2v[p][2], d2v[p][3])));
    }
    const float T = tenth_smallest(lmin, lane) * 1.000002f;

#pragma unroll
    for (int p = 0; p < 4; ++p) {
      const float mn = fminf(fminf(d2v[p][0], d2v[p][1]),
                             fminf(d2v[p][2], d2v[p][3]));
      if (mn <= T) {  // rare
        const int s = base + p * 256 + lane * 4;
#pragma unroll
        for (int j = 0; j < 4; ++j) {
          if (d2v[p][j] <= T) {
            const int pos = atomicAdd(&sh.tk.cnt[q], 1);
            if (pos < SCAP) sh.tk.cand[q][pos] = (unsigned)(s + j);
          }
        }
      }
    }

    __syncthreads();

    // ---- wave 0: exact strict-d top-10 over merged candidates ----
    if (q == 0) {
      unsigned long long top[NH_];
#pragma unroll
      for (int i = 0; i < NH_; ++i) top[i] = ~0ull;

#pragma unroll
      for (int seg = 0; seg < 8; ++seg) {
        const int nc = min(sh.tk.cnt[seg], SCAP);
#pragma unroll
        for (int cc = 0; cc < SCAP / 64; ++cc) {
          const int ci = lane + cc * 64;
          if (ci < nc) {
            const unsigned s = sh.tk.cand[seg][ci];
            const float lo = lon_row[s];
            const float la = lat_row[s];
            // bit-exact numpy sequence: mul, mul, add, sqrt — all rn
            const float d = __fsqrt_rn(__fadd_rn(__fmul_rn(lo, lo),
                                                 __fmul_rn(la, la)));
            unsigned long long p =
                ((unsigned long long)__float_as_uint(d) << 32) | s;
#pragma unroll
            for (int i = 0; i < NH_; ++i) {
              const bool lt = p < top[i];
              const unsigned long long mn2 = lt ? p : top[i];
              const unsigned long long mx2 = lt ? top[i] : p;
              top[i] = mn2;
              p = mx2;
            }
          }
        }
      }

      unsigned long long resv = ~0ull;
      unsigned long long cur = top[0];
#pragma unroll
      for (int k = 0; k < NH_; ++k) {
        unsigned long long m = cur;
#pragma unroll
        for (int off = 32; off > 0; off >>= 1) {
          const unsigned long long o = __shfl_xor(m, off, 64);
          m = o < m ? o : m;
        }
        if (cur == m) {
#pragma unroll
          for (int i = 0; i < NH_ - 1; ++i) top[i] = top[i + 1];
          top[NH_ - 1] = ~0ull;
          cur = top[0];
        }
        if (lane == k) resv = m;
      }

      if (lane < NH_) {
        const unsigned s = (unsigned)(resv & 0xffffffffu);
        const float d = __uint_as_float((unsigned)(resv >> 32));
        out_d[t * NH_ + lane] = d;
        idx_out[t * NH_ + lane] = (int)s;
        out_lon[t * NH_ + lane] = lon_row[s];
        out_lat[t * NH_ + lane] = lat_row[s];
      }
    }
  }
}

// ---------------------------------------------------------------------------
// Kernel B: x_nearest gather. (VERIFIED PASSING — unchanged. Runs LAST.)
// ---------------------------------------------------------------------------
__global__ __launch_bounds__(256) void gather_kernel(
    const float* __restrict__ x, const int* __restrict__ idxbuf,
    float* __restrict__ out_xn)
{
  const int t = blockIdx.x;
  __shared__ int sidx[NH_];
  if (threadIdx.x < NH_) sidx[threadIdx.x] = idxbuf[t * NH_ + threadIdx.x];
  __syncthreads();
  for (int i = threadIdx.x; i < B_ * NH_ * (E_ / 4); i += 256) {  // 640 items
    const int e4 = i & 7;
    const int k = (i >> 3) % NH_;
    const int b = (i >> 3) / NH_;
    const int s = sidx[k];
    const float4 v = *(const float4*)(x + ((size_t)b * NS_ + s) * E_ + e4 * 4);
    *(float4*)(out_xn + (((size_t)b * NT_ + t) * NH_ + k) * E_ + e4 * 4) = v;
  }
}

// ---------------------------------------------------------------------------
// Kernel P: x (f32 [b][s][e]) -> XT2 (bf16, GEMM-chunked layout).
// (VERIFIED PASSING — unchanged.)
// ---------------------------------------------------------------------------
__global__ __launch_bounds__(256) void xprep_kernel(
    const float* __restrict__ x, unsigned short* __restrict__ XT2)
{
  __shared__ __align__(16) unsigned short T[32][136];
  const int b = blockIdx.y;
  const int s0 = blockIdx.x * 128;
  const int tid = threadIdx.x;
  const int eq = tid & 7, slq = tid >> 3;
#pragma unroll
  for (int r4 = 0; r4 < 4; ++r4) {
    const int sl = r4 * 32 + slq;
    const float4 v = *(const float4*)&x[((size_t)b * NS_ + s0 + sl) * E_ + eq * 4];
    T[eq * 4 + 0][sl] = f2bf(v.x);
    T[eq * 4 + 1][sl] = f2bf(v.y);
    T[eq * 4 + 2][sl] = f2bf(v.z);
    T[eq * 4 + 3][sl] = f2bf(v.w);
  }
  __syncthreads();
  const int r = tid & 31, cq = tid >> 5;
  const int be = b * 32 + r;
  const int sA = s0 + cq * 16;
  const int c = sA >> 6;
  const int kA = (sA >> 3) & 7;
  unsigned short* dst = XT2 + ((size_t)(c * 8 + kA) * 256 + be) * 8;
  *(ushort8_t*)dst = *(const ushort8_t*)&T[r][cq * 16];
  *(ushort8_t*)(dst + 2048) = *(const ushort8_t*)&T[r][cq * 16 + 8];
}

// ---------------------------------------------------------------------------
extern "C" void kernel_launch(void* const* d_in, const int* in_sizes, int n_in,
                              void* d_out, int out_size, void* d_ws,
                              size_t ws_size, hipStream_t stream)
{
  const float* x       = (const float*)d_in[0];
  const float* rel_lon = (const float*)d_in[1];
  const float* rel_lat = (const float*)d_in[2];
  const float* cs      = (const float*)d_in[3];
  const float* ct      = (const float*)d_in[4];

  float* out = (float*)d_out;
  float* out_xn  = out;                                // (8,8192,10,32)
  float* out_xi  = out + (size_t)B_ * NT_ * NH_ * E_;  // (8,8192,32)
  float* out_d   = out_xi + (size_t)B_ * NT_ * E_;     // (8192,10)
  float* out_lon = out_d + (size_t)NT_ * NH_;
  float* out_lat = out_lon + (size_t)NT_ * NH_;

  int* idxbuf = (int*)d_ws;                       // 328 KB
  unsigned short* XT2 = (unsigned short*)out_xn;  // 4 MB scratch in out_xn;
                                                  // gather_kernel rewrites it.

  xprep_kernel<<<dim3(NS_ / 128, B_), 256, 0, stream>>>(x, XT2);
  mega_kernel<<<256 + NT_, 512, 0, stream>>>(rel_lon, rel_lat, out_d, out_lon,
                                             out_lat, idxbuf, XT2, cs, ct,
                                             out_xi);
  gather_kernel<<<NT_, 256, 0, stream>>>(x, idxbuf, out_xn);
}

// Round 17
// 252.515 us; speedup vs baseline: 1.0742x; 1.0742x over previous
//
#include <hip/hip_runtime.h>
#include <hip/hip_bf16.h>
#include <stdint.h>

#define B_   8
#define NS_  8192
#define E_   32
#define NT_  8192
#define NH_  10
#define NCH_ 128   // NS_/64 K-chunks
#define SCAP 128   // per-segment candidate cap (E~12 per 1024-elem segment)

typedef __bf16 bf16x8 __attribute__((ext_vector_type(8)));
typedef float  f32x4  __attribute__((ext_vector_type(4)));
typedef unsigned short ushort8_t __attribute__((ext_vector_type(8)));
typedef unsigned short ushort4_t __attribute__((ext_vector_type(4)));

static __device__ inline unsigned short f2bf(float f) {
  __hip_bfloat16 h = __float2bfloat16(f);
  return *reinterpret_cast<unsigned short*>(&h);
}
static __device__ inline float bf2f(unsigned short u) {
  __hip_bfloat16 h;
  *reinterpret_cast<unsigned short*>(&h) = u;
  return __bfloat162float(h);
}

// 10th-smallest of the 64 per-lane values (lane-tagged u64 keys; exact).
static __device__ inline float tenth_smallest(float v, int lane) {
  unsigned long long kv =
      ((unsigned long long)__float_as_uint(v) << 32) | (unsigned)lane;
  float out = 0.f;
#pragma unroll
  for (int k = 0; k < NH_; ++k) {
    unsigned long long m = kv;
#pragma unroll
    for (int off = 32; off > 0; off >>= 1) {
      const unsigned long long o = __shfl_xor(m, off, 64);
      m = o < m ? o : m;
    }
    if (kv == m) kv = ~0ull;  // self-remove (unique by lane tag)
    if (k == NH_ - 1) out = __uint_as_float((unsigned)(m >> 32));
  }
  return out;
}

// ---------------------------------------------------------------------------
// MEGA kernel (r15 configuration — empirically best: 254.6 us total).
// Grid-level fusion of xinter (blocks 0..255, VALU/MFMA-bound, ~1% HBM) and
// topk (blocks 256..8447, HBM-latency-bound, ~15% VALU). Disjoint pipes +
// no data dependency => co-resident overlap. xinter blocks first so each CU
// hosts ~1 xinter + 3 topk blocks (LDS 38.6KB/block => 4 blocks/CU).
// r16 lesson: finer pipeline (32-s chunks) doubled barriers, tripled bank
// conflicts, and setprio starved the critical-path topk waves => regression.
// ---------------------------------------------------------------------------
union __align__(16) SharedU {
  struct {
    unsigned short Xl[8][256][8];      // 32 KB (single-buffered A-tile)
    unsigned short Rl[2][8][16][8];    // 4 KB  (B-fragments, per-chunk)
    float RsumP[16][32];               // 2 KB
    float RsumInv[32];                 // 128 B
  } xi;
  struct {
    int cnt[8];
    unsigned int cand[8][SCAP];        // 4 KB
  } tk;
};

__global__ __launch_bounds__(512) void mega_kernel(
    const float* __restrict__ rel_lon, const float* __restrict__ rel_lat,
    float* __restrict__ out_d, float* __restrict__ out_lon,
    float* __restrict__ out_lat, int* __restrict__ idx_out,
    const unsigned short* __restrict__ XT2, const float* __restrict__ cs,
    const float* __restrict__ ct, float* __restrict__ out_xi)
{
#pragma clang fp contract(off)
  __shared__ SharedU sh;
  const int tid = threadIdx.x;

  if (blockIdx.x < 256) {
    // =====================================================================
    // xinter path (VERIFIED r8-r15 pipeline, single-buffered):
    //   out[be][t] = (sum_s XT[be][s] * r(t,s)) / rsum[t]
    // 8 waves = 4 mg x 2 ng; per chunk: stage A-tile (global_load_lds),
    // gen 32t x 64s r-tile once (strict bit-exact d2, r=rsq), MFMA.
    // =====================================================================
    const int w = tid >> 6, l = tid & 63;
    const int mg = w >> 1, ng = w & 1;
    const int lcol = l & 15, lkg = l >> 4;
    const int t0 = blockIdx.x * 32;

    const int gt = tid & 31;
    const int gq = tid >> 5;
    const int gng = gt >> 4, glc = gt & 15;
    const int gk = gq >> 1;
    const int gsl = (gq & 1) * 4;
    const float2 ctg = ((const float2*)ct)[t0 + gt];
    const float t2g = ctg.x * ctg.x + ctg.y * ctg.y;   // strict rn
    float rpart = 0.f;

    const int t = t0 + ng * 16 + lcol;

    f32x4 acc[4];
#pragma unroll
    for (int m = 0; m < 4; ++m)
#pragma unroll
      for (int j = 0; j < 4; ++j) acc[m][j] = 0.f;

    for (int c = 0; c < NCH_; ++c) {
      // ---- stage chunk c: wave w fills Xl[w][be][0..7] (coalesced) ----
      {
        const unsigned short* gsrc =
            XT2 + ((size_t)c * 8 + w) * 2048 + (size_t)l * 8;
#pragma unroll
        for (int bg = 0; bg < 4; ++bg) {
          __builtin_amdgcn_global_load_lds(
              (const __attribute__((address_space(1))) void*)(gsrc + bg * 512),
              (__attribute__((address_space(3))) void*)&sh.xi.Xl[w][bg * 64][0],
              16, 0, 0);
        }
      }
      // ---- gen r-tile (strict bit-exact d2 path; overlaps staging) ----
      {
        const int sb = c * 64 + gq * 4;
        const float4 cA = *(const float4*)&cs[2 * sb];
        const float4 cB = *(const float4*)&cs[2 * sb + 4];
        const float sxv[4] = {cA.x, cA.z, cB.x, cB.z};
        const float syv[4] = {cA.y, cA.w, cB.y, cB.w};
        ushort4_t ro;
#pragma unroll
        for (int j = 0; j < 4; ++j) {
          const float sx = sxv[j], sy = syv[j];
          const float s2 = sx * sx + sy * sy;        // strict rn
          const float p0 = ctg.x * sx;               // strict rn, k=0
          const float dot = fmaf(ctg.y, sy, p0);     // explicit fma, k=1
          const float ts = t2g + s2;                 // strict rn
          float d2 = ts - 2.0f * dot;                // 2*dot exact
          d2 = fmaxf(d2, 1e-12f);
          const float r = __builtin_amdgcn_rsqf(d2);
          const unsigned short ub = f2bf(r);
          ro[j] = ub;
          rpart += bf2f(ub);
        }
        *(ushort4_t*)&sh.xi.Rl[gng][gk][glc][gsl] = ro;
      }
      asm volatile("s_waitcnt vmcnt(0) lgkmcnt(0)" ::: "memory");
      __builtin_amdgcn_s_barrier();   // Xl + Rl ready for all waves

#pragma unroll
      for (int half = 0; half < 2; ++half) {
        const bf16x8 Bf = *(const bf16x8*)&sh.xi.Rl[ng][half * 4 + lkg][lcol][0];
#pragma unroll
        for (int m = 0; m < 4; ++m) {
          const bf16x8 a = *(const bf16x8*)
              &sh.xi.Xl[half * 4 + lkg][(mg * 4 + m) * 16 + lcol][0];
          acc[m] =
              __builtin_amdgcn_mfma_f32_16x16x32_bf16(a, Bf, acc[m], 0, 0, 0);
        }
      }
      __builtin_amdgcn_s_barrier();   // MFMA reads done before next overwrite
    }

    // ---- rsum reduction: 16 partials per t ----
    sh.xi.RsumP[gq][gt] = rpart;
    asm volatile("s_waitcnt lgkmcnt(0)" ::: "memory");
    __builtin_amdgcn_s_barrier();
    if (tid < 32) {
      float ssum = 0.f;
#pragma unroll
      for (int qq = 0; qq < 16; ++qq) ssum += sh.xi.RsumP[qq][tid];
      sh.xi.RsumInv[tid] = 1.0f / ssum;
    }
    asm volatile("s_waitcnt lgkmcnt(0)" ::: "memory");
    __builtin_amdgcn_s_barrier();
    const float ri = sh.xi.RsumInv[ng * 16 + lcol];

    // C/D layout: lane l reg j -> row(be) = lkg*4 + j, col(t) = lcol.
#pragma unroll
    for (int m = 0; m < 4; ++m) {
      const int be0 = (mg * 4 + m) * 16 + lkg * 4;
      const int b = be0 >> 5, e = be0 & 31;
      float4 o;
      o.x = acc[m][0] * ri;
      o.y = acc[m][1] * ri;
      o.z = acc[m][2] * ri;
      o.w = acc[m][3] * ri;
      *(float4*)&out_xi[((size_t)b * NT_ + t) * E_ + e] = o;
    }
  } else {
    // =====================================================================
    // topk path (r13/r15 VERIFIED structure, 8 segments of 1024 elems):
    //  per wave: 4 packets -> d2 in regs; T = tenth_smallest(lane-min of
    //  whole segment) * 1.000002 (distinct-elements upper bound + margin);
    //  collect from register d2; wave 0 runs the exact strict-rn machinery
    //  (bit-identical to numpy incl. tie-breaking).
    // =====================================================================
    const int q = tid >> 6;       // segment index (0..7)
    const int lane = tid & 63;
    const int t = blockIdx.x - 256;
    const float* lon_row = rel_lon + (size_t)t * NS_;
    const float* lat_row = rel_lat + (size_t)t * NS_;
    const int base = q * 1024;
    const float4* lon4 = (const float4*)(lon_row + base);
    const float4* lat4 = (const float4*)(lat_row + base);

    if (lane == 0) sh.tk.cnt[q] = 0;

    float d2v[4][4];
    float lmin = __uint_as_float(0x7f800000u);  // +inf
#pragma unroll
    for (int p = 0; p < 4; ++p) {
      const float4 lo = lon4[p * 64 + lane];
      const float4 la = lat4[p * 64 + lane];
      d2v[p][0] = __fmaf_rn(lo.x, lo.x, __fmul_rn(la.x, la.x));
      d2v[p][1] = __fmaf_rn(lo.y, lo.y, __fmul_rn(la.y, la.y));
      d2v[p][2] = __fmaf_rn(lo.z, lo.z, __fmul_rn(la.z, la.z));
      d2v[p][3] = __fmaf_rn(lo.w, lo.w, __fmul_rn(la.w, la.w));
      lmin = fminf(lmin, fminf(fminf(d2v[p][0], d2v[p][1]),
                               fminf(d2v[p][2], d2v[p][3])));
    }
    const float T = tenth_smallest(lmin, lane) * 1.000002f;

#pragma unroll
    for (int p = 0; p < 4; ++p) {
      const float mn = fminf(fminf(d2v[p][0], d2v[p][1]),
                             fminf(d2v[p][2], d2v[p][3]));
      if (mn <= T) {  // rare
        const int s = base + p * 256 + lane * 4;
#pragma unroll
        for (int j = 0; j < 4; ++j) {
          if (d2v[p][j] <= T) {
            const int pos = atomicAdd(&sh.tk.cnt[q], 1);
            if (pos < SCAP) sh.tk.cand[q][pos] = (unsigned)(s + j);
          }
        }
      }
    }

    __syncthreads();

    // ---- wave 0: exact strict-d top-10 over merged candidates ----
    if (q == 0) {
      unsigned long long top[NH_];
#pragma unroll
      for (int i = 0; i < NH_; ++i) top[i] = ~0ull;

#pragma unroll
      for (int seg = 0; seg < 8; ++seg) {
        const int nc = min(sh.tk.cnt[seg], SCAP);
#pragma unroll
        for (int cc = 0; cc < SCAP / 64; ++cc) {
          const int ci = lane + cc * 64;
          if (ci < nc) {
            const unsigned s = sh.tk.cand[seg][ci];
            const float lo = lon_row[s];
            const float la = lat_row[s];
            // bit-exact numpy sequence: mul, mul, add, sqrt — all rn
            const float d = __fsqrt_rn(__fadd_rn(__fmul_rn(lo, lo),
                                                 __fmul_rn(la, la)));
            unsigned long long p =
                ((unsigned long long)__float_as_uint(d) << 32) | s;
#pragma unroll
            for (int i = 0; i < NH_; ++i) {
              const bool lt = p < top[i];
              const unsigned long long mn2 = lt ? p : top[i];
              const unsigned long long mx2 = lt ? top[i] : p;
              top[i] = mn2;
              p = mx2;
            }
          }
        }
      }

      unsigned long long resv = ~0ull;
      unsigned long long cur = top[0];
#pragma unroll
      for (int k = 0; k < NH_; ++k) {
        unsigned long long m = cur;
#pragma unroll
        for (int off = 32; off > 0; off >>= 1) {
          const unsigned long long o = __shfl_xor(m, off, 64);
          m = o < m ? o : m;
        }
        if (cur == m) {
#pragma unroll
          for (int i = 0; i < NH_ - 1; ++i) top[i] = top[i + 1];
          top[NH_ - 1] = ~0ull;
          cur = top[0];
        }
        if (lane == k) resv = m;
      }

      if (lane < NH_) {
        const unsigned s = (unsigned)(resv & 0xffffffffu);
        const float d = __uint_as_float((unsigned)(resv >> 32));
        out_d[t * NH_ + lane] = d;
        idx_out[t * NH_ + lane] = (int)s;
        out_lon[t * NH_ + lane] = lon_row[s];
        out_lat[t * NH_ + lane] = lat_row[s];
      }
    }
  }
}

// ---------------------------------------------------------------------------
// Kernel B: x_nearest gather. (VERIFIED PASSING — unchanged. Runs LAST.)
// ---------------------------------------------------------------------------
__global__ __launch_bounds__(256) void gather_kernel(
    const float* __restrict__ x, const int* __restrict__ idxbuf,
    float* __restrict__ out_xn)
{
  const int t = blockIdx.x;
  __shared__ int sidx[NH_];
  if (threadIdx.x < NH_) sidx[threadIdx.x] = idxbuf[t * NH_ + threadIdx.x];
  __syncthreads();
  for (int i = threadIdx.x; i < B_ * NH_ * (E_ / 4); i += 256) {  // 640 items
    const int e4 = i & 7;
    const int k = (i >> 3) % NH_;
    const int b = (i >> 3) / NH_;
    const int s = sidx[k];
    const float4 v = *(const float4*)(x + ((size_t)b * NS_ + s) * E_ + e4 * 4);
    *(float4*)(out_xn + (((size_t)b * NT_ + t) * NH_ + k) * E_ + e4 * 4) = v;
  }
}

// ---------------------------------------------------------------------------
// Kernel P: x (f32 [b][s][e]) -> XT2 (bf16, GEMM-chunked layout).
// (VERIFIED PASSING — unchanged.)
// ---------------------------------------------------------------------------
__global__ __launch_bounds__(256) void xprep_kernel(
    const float* __restrict__ x, unsigned short* __restrict__ XT2)
{
  __shared__ __align__(16) unsigned short T[32][136];
  const int b = blockIdx.y;
  const int s0 = blockIdx.x * 128;
  const int tid = threadIdx.x;
  const int eq = tid & 7, slq = tid >> 3;
#pragma unroll
  for (int r4 = 0; r4 < 4; ++r4) {
    const int sl = r4 * 32 + slq;
    const float4 v = *(const float4*)&x[((size_t)b * NS_ + s0 + sl) * E_ + eq * 4];
    T[eq * 4 + 0][sl] = f2bf(v.x);
    T[eq * 4 + 1][sl] = f2bf(v.y);
    T[eq * 4 + 2][sl] = f2bf(v.z);
    T[eq * 4 + 3][sl] = f2bf(v.w);
  }
  __syncthreads();
  const int r = tid & 31, cq = tid >> 5;
  const int be = b * 32 + r;
  const int sA = s0 + cq * 16;
  const int c = sA >> 6;
  const int kA = (sA >> 3) & 7;
  unsigned short* dst = XT2 + ((size_t)(c * 8 + kA) * 256 + be) * 8;
  *(ushort8_t*)dst = *(const ushort8_t*)&T[r][cq * 16];
  *(ushort8_t*)(dst + 2048) = *(const ushort8_t*)&T[r][cq * 16 + 8];
}

// ---------------------------------------------------------------------------
extern "C" void kernel_launch(void* const* d_in, const int* in_sizes, int n_in,
                              void* d_out, int out_size, void* d_ws,
                              size_t ws_size, hipStream_t stream)
{
  const float* x       = (const float*)d_in[0];
  const float* rel_lon = (const float*)d_in[1];
  const float* rel_lat = (const float*)d_in[2];
  const float* cs      = (const float*)d_in[3];
  const float* ct      = (const float*)d_in[4];

  float* out = (float*)d_out;
  float* out_xn  = out;                                // (8,8192,10,32)
  float* out_xi  = out + (size_t)B_ * NT_ * NH_ * E_;  // (8,8192,32)
  float* out_d   = out_xi + (size_t)B_ * NT_ * E_;     // (8192,10)
  float* out_lon = out_d + (size_t)NT_ * NH_;
  float* out_lat = out_lon + (size_t)NT_ * NH_;

  int* idxbuf = (int*)d_ws;                       // 328 KB
  unsigned short* XT2 = (unsigned short*)out_xn;  // 4 MB scratch in out_xn;
                                                  // gather_kernel rewrites it.

  xprep_kernel<<<dim3(NS_ / 128, B_), 256, 0, stream>>>(x, XT2);
  mega_kernel<<<256 + NT_, 512, 0, stream>>>(rel_lon, rel_lat, out_d, out_lon,
                                             out_lat, idxbuf, XT2, cs, ct,
                                             out_xi);
  gather_kernel<<<NT_, 256, 0, stream>>>(x, idxbuf, out_xn);
}